// Round 2
// baseline (509.313 us; speedup 1.0000x reference)
//
#include <hip/hip_runtime.h>

// Problem constants (fixed by the reference file)
constexpr int B  = 2;
constexpr int X  = 128, Y = 128, Z = 128, C = 4;
constexpr int OX = 96,  OY = 96,  OZ = 96;
constexpr int NPTS = B * OX * OY * OZ;          // 1,769,472 output voxels
constexpr int PTS_PER_BATCH = OX * OY * OZ;     // 884,736

// Spatial binning: 16^3-voxel cells -> 8 cells/dim -> 512 cells/batch, 1024 bins.
constexpr int CELL_SHIFT = 4;                    // 16 voxels per cell
constexpr int CPD = X >> CELL_SHIFT;             // 8 cells per dim
constexpr int NBINS = B * CPD * CPD * CPD;       // 1024

// Workspace layout
constexpr size_t REC_BYTES   = (size_t)NPTS * 16;       // float4 records
constexpr size_t CNT_OFF     = REC_BYTES;               // int counts[NBINS]
constexpr size_t CUR_OFF     = CNT_OFF + 4096;          // int cursors[NBINS]
constexpr size_t WS_NEEDED   = CUR_OFF + 4096;

__device__ __forceinline__ int point_bin(float cx, float cy, float cz, int b) {
    int x = min(max((int)floorf(cx), 0), X - 1) >> CELL_SHIFT;
    int y = min(max((int)floorf(cy), 0), Y - 1) >> CELL_SHIFT;
    int z = min(max((int)floorf(cz), 0), Z - 1) >> CELL_SHIFT;
    return (((b * CPD + x) * CPD + y) * CPD + z);
}

// K1: per-block LDS histogram of bin occupancy, merged with global atomics.
__global__ __launch_bounds__(256) void hist_kernel(
    const float* __restrict__ coords, int* __restrict__ counts)
{
    __shared__ int h[NBINS];
    for (int i = threadIdx.x; i < NBINS; i += 256) h[i] = 0;
    __syncthreads();
    for (int idx = blockIdx.x * 256 + threadIdx.x; idx < NPTS;
         idx += gridDim.x * 256) {
        const float cx = coords[(size_t)idx * 3 + 0];
        const float cy = coords[(size_t)idx * 3 + 1];
        const float cz = coords[(size_t)idx * 3 + 2];
        const int b = idx / PTS_PER_BATCH;
        atomicAdd(&h[point_bin(cx, cy, cz, b)], 1);
    }
    __syncthreads();
    for (int i = threadIdx.x; i < NBINS; i += 256)
        if (h[i]) atomicAdd(&counts[i], h[i]);
}

// K2: single-block exclusive scan of counts -> cursors (scatter base offsets).
__global__ __launch_bounds__(1024) void scan_kernel(
    const int* __restrict__ counts, int* __restrict__ cursors)
{
    __shared__ int s[NBINS];
    const int t = threadIdx.x;
    const int c = counts[t];
    s[t] = c;
    __syncthreads();
    #pragma unroll
    for (int off = 1; off < NBINS; off <<= 1) {
        int add = (t >= off) ? s[t - off] : 0;
        __syncthreads();
        s[t] += add;
        __syncthreads();
    }
    cursors[t] = s[t] - c;   // exclusive prefix
}

// K3: scatter point records {cx,cy,cz,tid} into bin-sorted order.
__global__ __launch_bounds__(256) void scatter_kernel(
    const float* __restrict__ coords, int* __restrict__ cursors,
    float4* __restrict__ records)
{
    for (int idx = blockIdx.x * 256 + threadIdx.x; idx < NPTS;
         idx += gridDim.x * 256) {
        const float cx = coords[(size_t)idx * 3 + 0];
        const float cy = coords[(size_t)idx * 3 + 1];
        const float cz = coords[(size_t)idx * 3 + 2];
        const int b = idx / PTS_PER_BATCH;
        const int bin = point_bin(cx, cy, cz, b);
        const int pos = atomicAdd(&cursors[bin], 1);
        records[pos] = make_float4(cx, cy, cz, __int_as_float(idx));
    }
}

// K4: process bin-sorted records; gathers now have strong spatial locality.
// 4 points/thread, 1024 points/block; XCD-chunked block swizzle so a bin's
// blocks stay on one XCD's L2.
constexpr int K4_PTS_PER_BLK = 1024;
constexpr int K4_NBLK = NPTS / K4_PTS_PER_BLK;   // 1728 (exact)
constexpr int NXCD = 8;
constexpr int K4_CPX = K4_NBLK / NXCD;           // 216 (exact)

__global__ __launch_bounds__(256) void process_kernel(
    const float* __restrict__ inp, const float4* __restrict__ records,
    float4* __restrict__ out)
{
    const int pb = blockIdx.x;
    const int chunk = (pb & (NXCD - 1)) * K4_CPX + (pb >> 3);  // bijective: 1728%8==0
    const int base = chunk * K4_PTS_PER_BLK;

    #pragma unroll
    for (int p = 0; p < 4; ++p) {
        const int i = base + p * 256 + threadIdx.x;
        const float4 rec = records[i];
        const float cx = rec.x, cy = rec.y, cz = rec.z;
        const int tid = __float_as_int(rec.w);
        const int b = tid / PTS_PER_BATCH;

        const float bx = floorf(cx), by = floorf(cy), bz = floorf(cz);
        const float wx0 = cx - bx, wy0 = cy - by, wz0 = cz - bz;
        const float wx1 = 1.0f - wx0, wy1 = 1.0f - wy0, wz1 = 1.0f - wz0;

        const int x0 = (int)fminf(fmaxf(bx,        0.0f), (float)(X - 1));
        const int x1 = (int)fminf(fmaxf(bx + 1.0f, 0.0f), (float)(X - 1));
        const int y0 = (int)fminf(fmaxf(by,        0.0f), (float)(Y - 1));
        const int y1 = (int)fminf(fmaxf(by + 1.0f, 0.0f), (float)(Y - 1));
        const int z0 = (int)fminf(fmaxf(bz,        0.0f), (float)(Z - 1));
        const int z1 = (int)fminf(fmaxf(bz + 1.0f, 0.0f), (float)(Z - 1));

        const float4* in4 = (const float4*)inp + (size_t)b * X * Y * Z;
        const int xo0 = x0 * (Y * Z), xo1 = x1 * (Y * Z);
        const int yo0 = y0 * Z,       yo1 = y1 * Z;

        const float4 v000 = in4[xo0 + yo0 + z0];
        const float4 v001 = in4[xo0 + yo0 + z1];
        const float4 v010 = in4[xo0 + yo1 + z0];
        const float4 v011 = in4[xo0 + yo1 + z1];
        const float4 v100 = in4[xo1 + yo0 + z0];
        const float4 v101 = in4[xo1 + yo0 + z1];
        const float4 v110 = in4[xo1 + yo1 + z0];
        const float4 v111 = in4[xo1 + yo1 + z1];

        float4 r;
        #define LERP4(a, b_, wA, wB, dst)                  \
            dst.x = (a).x * (wA) + (b_).x * (wB);          \
            dst.y = (a).y * (wA) + (b_).y * (wB);          \
            dst.z = (a).z * (wA) + (b_).z * (wB);          \
            dst.w = (a).w * (wA) + (b_).w * (wB);
        float4 c00, c01, c10, c11, c0, c1;
        LERP4(v000, v001, wz1, wz0, c00);
        LERP4(v010, v011, wz1, wz0, c01);
        LERP4(v100, v101, wz1, wz0, c10);
        LERP4(v110, v111, wz1, wz0, c11);
        LERP4(c00, c01, wy1, wy0, c0);
        LERP4(c10, c11, wy1, wy0, c1);
        LERP4(c0, c1, wx1, wx0, r);
        #undef LERP4

        out[tid] = r;   // scattered 16B store
    }
}

// Fallback (round-1 kernel) if workspace is too small for the sort pipeline.
__global__ __launch_bounds__(256) void resampler_direct_kernel(
    const float* __restrict__ inp, const float* __restrict__ coords,
    float4* __restrict__ out)
{
    const int tid = blockIdx.x * blockDim.x + threadIdx.x;
    if (tid >= NPTS) return;
    const int b = tid / PTS_PER_BATCH;
    const float cx = coords[(size_t)tid * 3 + 0];
    const float cy = coords[(size_t)tid * 3 + 1];
    const float cz = coords[(size_t)tid * 3 + 2];
    const float bx = floorf(cx), by = floorf(cy), bz = floorf(cz);
    const float wx0 = cx - bx, wy0 = cy - by, wz0 = cz - bz;
    const float wx1 = 1.0f - wx0, wy1 = 1.0f - wy0, wz1 = 1.0f - wz0;
    const int x0 = (int)fminf(fmaxf(bx,        0.0f), (float)(X - 1));
    const int x1 = (int)fminf(fmaxf(bx + 1.0f, 0.0f), (float)(X - 1));
    const int y0 = (int)fminf(fmaxf(by,        0.0f), (float)(Y - 1));
    const int y1 = (int)fminf(fmaxf(by + 1.0f, 0.0f), (float)(Y - 1));
    const int z0 = (int)fminf(fmaxf(bz,        0.0f), (float)(Z - 1));
    const int z1 = (int)fminf(fmaxf(bz + 1.0f, 0.0f), (float)(Z - 1));
    const float4* in4 = (const float4*)inp + (size_t)b * X * Y * Z;
    const int xo0 = x0 * (Y * Z), xo1 = x1 * (Y * Z);
    const int yo0 = y0 * Z,       yo1 = y1 * Z;
    const float4 v000 = in4[xo0 + yo0 + z0];
    const float4 v001 = in4[xo0 + yo0 + z1];
    const float4 v010 = in4[xo0 + yo1 + z0];
    const float4 v011 = in4[xo0 + yo1 + z1];
    const float4 v100 = in4[xo1 + yo0 + z0];
    const float4 v101 = in4[xo1 + yo0 + z1];
    const float4 v110 = in4[xo1 + yo1 + z0];
    const float4 v111 = in4[xo1 + yo1 + z1];
    float4 r;
    #define LERP4(a, b_, wA, wB, dst)                  \
        dst.x = (a).x * (wA) + (b_).x * (wB);          \
        dst.y = (a).y * (wA) + (b_).y * (wB);          \
        dst.z = (a).z * (wA) + (b_).z * (wB);          \
        dst.w = (a).w * (wA) + (b_).w * (wB);
    float4 c00, c01, c10, c11, c0, c1;
    LERP4(v000, v001, wz1, wz0, c00);
    LERP4(v010, v011, wz1, wz0, c01);
    LERP4(v100, v101, wz1, wz0, c10);
    LERP4(v110, v111, wz1, wz0, c11);
    LERP4(c00, c01, wy1, wy0, c0);
    LERP4(c10, c11, wy1, wy0, c1);
    LERP4(c0, c1, wx1, wx0, r);
    #undef LERP4
    out[tid] = r;
}

extern "C" void kernel_launch(void* const* d_in, const int* in_sizes, int n_in,
                              void* d_out, int out_size, void* d_ws, size_t ws_size,
                              hipStream_t stream) {
    const float* inp    = (const float*)d_in[0];
    const float* coords = (const float*)d_in[1];
    float4* out = (float4*)d_out;

    if (ws_size < WS_NEEDED) {
        // Not enough scratch — direct (round-1) path.
        const int blocks = (NPTS + 255) / 256;
        resampler_direct_kernel<<<blocks, 256, 0, stream>>>(inp, coords, out);
        return;
    }

    char* ws = (char*)d_ws;
    float4* records = (float4*)ws;
    int* counts  = (int*)(ws + CNT_OFF);
    int* cursors = (int*)(ws + CUR_OFF);

    hipMemsetAsync(counts, 0, NBINS * sizeof(int), stream);
    hist_kernel<<<512, 256, 0, stream>>>(coords, counts);
    scan_kernel<<<1, NBINS, 0, stream>>>(counts, cursors);
    scatter_kernel<<<2048, 256, 0, stream>>>(coords, cursors, records);
    process_kernel<<<K4_NBLK, 256, 0, stream>>>(inp, records, out);
}

// Round 3
// 119.770 us; speedup vs baseline: 4.2524x; 4.2524x over previous
//
#include <hip/hip_runtime.h>

// Problem constants (fixed by the reference file)
constexpr int B  = 2;
constexpr int X  = 128, Y = 128, Z = 128, C = 4;
constexpr int OX = 96,  OY = 96,  OZ = 96;
constexpr int NPTS = B * OX * OY * OZ;          // 1,769,472 output voxels
constexpr int PTS_PER_BATCH = OX * OY * OZ;     // 884,736

// Spatial binning: 16^3-voxel cells -> 8 cells/dim -> 512 cells/batch, 1024 bins.
constexpr int CELL_SHIFT = 4;                    // 16 voxels per cell
constexpr int CPD = X >> CELL_SHIFT;             // 8 cells per dim
constexpr int NBINS = B * CPD * CPD * CPD;       // 1024

// Workspace layout
constexpr size_t REC_BYTES   = (size_t)NPTS * 16;       // float4 records
constexpr size_t CNT_OFF     = REC_BYTES;               // int counts[NBINS]
constexpr size_t CUR_OFF     = CNT_OFF + 4096;          // int cursors[NBINS]
constexpr size_t WS_NEEDED   = CUR_OFF + 4096;

__device__ __forceinline__ int point_bin(float cx, float cy, float cz, int b) {
    int x = min(max((int)floorf(cx), 0), X - 1) >> CELL_SHIFT;
    int y = min(max((int)floorf(cy), 0), Y - 1) >> CELL_SHIFT;
    int z = min(max((int)floorf(cz), 0), Z - 1) >> CELL_SHIFT;
    return (((b * CPD + x) * CPD + y) * CPD + z);
}

// K1: per-block LDS histogram of bin occupancy, merged with global atomics.
__global__ __launch_bounds__(256) void hist_kernel(
    const float* __restrict__ coords, int* __restrict__ counts)
{
    __shared__ int h[NBINS];
    for (int i = threadIdx.x; i < NBINS; i += 256) h[i] = 0;
    __syncthreads();
    for (int idx = blockIdx.x * 256 + threadIdx.x; idx < NPTS;
         idx += gridDim.x * 256) {
        const float cx = coords[(size_t)idx * 3 + 0];
        const float cy = coords[(size_t)idx * 3 + 1];
        const float cz = coords[(size_t)idx * 3 + 2];
        const int b = idx / PTS_PER_BATCH;
        atomicAdd(&h[point_bin(cx, cy, cz, b)], 1);
    }
    __syncthreads();
    for (int i = threadIdx.x; i < NBINS; i += 256)
        if (h[i]) atomicAdd(&counts[i], h[i]);
}

// K2: single-block exclusive scan of counts -> cursors (scatter base offsets).
__global__ __launch_bounds__(1024) void scan_kernel(
    const int* __restrict__ counts, int* __restrict__ cursors)
{
    __shared__ int s[NBINS];
    const int t = threadIdx.x;
    const int c = counts[t];
    s[t] = c;
    __syncthreads();
    #pragma unroll
    for (int off = 1; off < NBINS; off <<= 1) {
        int add = (t >= off) ? s[t - off] : 0;
        __syncthreads();
        s[t] += add;
        __syncthreads();
    }
    cursors[t] = s[t] - c;   // exclusive prefix
}

// K3: LDS-aggregated two-phase scatter.
// 108 blocks x 1024 threads x 16 pts = NPTS exactly.
// Phase A: LDS histogram of this block's 16384 points (LDS atomics).
// Phase B: ONE global atomicAdd per occupied bin reserves a range
//          (<=1024 global atomics/block vs 16384 per-point before).
// Phase C: place points via LDS sub-cursors; write records.
constexpr int SC_THREADS = 1024;
constexpr int SC_PPT     = 16;
constexpr int SC_PPB     = SC_THREADS * SC_PPT;          // 16384
constexpr int SC_NBLK    = NPTS / SC_PPB;                // 108 (exact)

__global__ __launch_bounds__(SC_THREADS) void scatter_kernel(
    const float* __restrict__ coords, int* __restrict__ cursors,
    float4* __restrict__ records)
{
    __shared__ int h[NBINS];      // phase A: counts; phase C: sub-cursors
    __shared__ int base[NBINS];   // phase B: global base per bin
    const int t = threadIdx.x;
    const int blkBase = blockIdx.x * SC_PPB;

    h[t] = 0;                     // SC_THREADS == NBINS
    __syncthreads();

    int bins[SC_PPT];
    #pragma unroll
    for (int p = 0; p < SC_PPT; ++p) {
        const int idx = blkBase + p * SC_THREADS + t;
        const float cx = coords[(size_t)idx * 3 + 0];
        const float cy = coords[(size_t)idx * 3 + 1];
        const float cz = coords[(size_t)idx * 3 + 2];
        const int b = idx / PTS_PER_BATCH;
        bins[p] = point_bin(cx, cy, cz, b);
        atomicAdd(&h[bins[p]], 1);
    }
    __syncthreads();

    const int cnt = h[t];
    base[t] = cnt ? atomicAdd(&cursors[t], cnt) : 0;
    __syncthreads();
    h[t] = 0;                     // reuse as sub-cursor
    __syncthreads();

    #pragma unroll
    for (int p = 0; p < SC_PPT; ++p) {
        const int idx = blkBase + p * SC_THREADS + t;
        const float cx = coords[(size_t)idx * 3 + 0];   // L2/L3-hot re-read
        const float cy = coords[(size_t)idx * 3 + 1];
        const float cz = coords[(size_t)idx * 3 + 2];
        const int pos = base[bins[p]] + atomicAdd(&h[bins[p]], 1);
        records[pos] = make_float4(cx, cy, cz, __int_as_float(idx));
    }
}

// K4: process bin-sorted records; gathers now have strong spatial locality.
// 4 points/thread, 1024 points/block; XCD-chunked block swizzle so a bin's
// blocks stay on one XCD's L2.
constexpr int K4_PTS_PER_BLK = 1024;
constexpr int K4_NBLK = NPTS / K4_PTS_PER_BLK;   // 1728 (exact)
constexpr int NXCD = 8;
constexpr int K4_CPX = K4_NBLK / NXCD;           // 216 (exact)

__global__ __launch_bounds__(256) void process_kernel(
    const float* __restrict__ inp, const float4* __restrict__ records,
    float4* __restrict__ out)
{
    const int pb = blockIdx.x;
    const int chunk = (pb & (NXCD - 1)) * K4_CPX + (pb >> 3);  // bijective: 1728%8==0
    const int base = chunk * K4_PTS_PER_BLK;

    #pragma unroll
    for (int p = 0; p < 4; ++p) {
        const int i = base + p * 256 + threadIdx.x;
        const float4 rec = records[i];
        const float cx = rec.x, cy = rec.y, cz = rec.z;
        const int tid = __float_as_int(rec.w);
        const int b = tid / PTS_PER_BATCH;

        const float bx = floorf(cx), by = floorf(cy), bz = floorf(cz);
        const float wx0 = cx - bx, wy0 = cy - by, wz0 = cz - bz;
        const float wx1 = 1.0f - wx0, wy1 = 1.0f - wy0, wz1 = 1.0f - wz0;

        const int x0 = (int)fminf(fmaxf(bx,        0.0f), (float)(X - 1));
        const int x1 = (int)fminf(fmaxf(bx + 1.0f, 0.0f), (float)(X - 1));
        const int y0 = (int)fminf(fmaxf(by,        0.0f), (float)(Y - 1));
        const int y1 = (int)fminf(fmaxf(by + 1.0f, 0.0f), (float)(Y - 1));
        const int z0 = (int)fminf(fmaxf(bz,        0.0f), (float)(Z - 1));
        const int z1 = (int)fminf(fmaxf(bz + 1.0f, 0.0f), (float)(Z - 1));

        const float4* in4 = (const float4*)inp + (size_t)b * X * Y * Z;
        const int xo0 = x0 * (Y * Z), xo1 = x1 * (Y * Z);
        const int yo0 = y0 * Z,       yo1 = y1 * Z;

        const float4 v000 = in4[xo0 + yo0 + z0];
        const float4 v001 = in4[xo0 + yo0 + z1];
        const float4 v010 = in4[xo0 + yo1 + z0];
        const float4 v011 = in4[xo0 + yo1 + z1];
        const float4 v100 = in4[xo1 + yo0 + z0];
        const float4 v101 = in4[xo1 + yo0 + z1];
        const float4 v110 = in4[xo1 + yo1 + z0];
        const float4 v111 = in4[xo1 + yo1 + z1];

        float4 r;
        #define LERP4(a, b_, wA, wB, dst)                  \
            dst.x = (a).x * (wA) + (b_).x * (wB);          \
            dst.y = (a).y * (wA) + (b_).y * (wB);          \
            dst.z = (a).z * (wA) + (b_).z * (wB);          \
            dst.w = (a).w * (wA) + (b_).w * (wB);
        float4 c00, c01, c10, c11, c0, c1;
        LERP4(v000, v001, wz1, wz0, c00);
        LERP4(v010, v011, wz1, wz0, c01);
        LERP4(v100, v101, wz1, wz0, c10);
        LERP4(v110, v111, wz1, wz0, c11);
        LERP4(c00, c01, wy1, wy0, c0);
        LERP4(c10, c11, wy1, wy0, c1);
        LERP4(c0, c1, wx1, wx0, r);
        #undef LERP4

        out[tid] = r;   // scattered 16B store
    }
}

// Fallback (round-1 kernel) if workspace is too small for the sort pipeline.
__global__ __launch_bounds__(256) void resampler_direct_kernel(
    const float* __restrict__ inp, const float* __restrict__ coords,
    float4* __restrict__ out)
{
    const int tid = blockIdx.x * blockDim.x + threadIdx.x;
    if (tid >= NPTS) return;
    const int b = tid / PTS_PER_BATCH;
    const float cx = coords[(size_t)tid * 3 + 0];
    const float cy = coords[(size_t)tid * 3 + 1];
    const float cz = coords[(size_t)tid * 3 + 2];
    const float bx = floorf(cx), by = floorf(cy), bz = floorf(cz);
    const float wx0 = cx - bx, wy0 = cy - by, wz0 = cz - bz;
    const float wx1 = 1.0f - wx0, wy1 = 1.0f - wy0, wz1 = 1.0f - wz0;
    const int x0 = (int)fminf(fmaxf(bx,        0.0f), (float)(X - 1));
    const int x1 = (int)fminf(fmaxf(bx + 1.0f, 0.0f), (float)(X - 1));
    const int y0 = (int)fminf(fmaxf(by,        0.0f), (float)(Y - 1));
    const int y1 = (int)fminf(fmaxf(by + 1.0f, 0.0f), (float)(Y - 1));
    const int z0 = (int)fminf(fmaxf(bz,        0.0f), (float)(Z - 1));
    const int z1 = (int)fminf(fmaxf(bz + 1.0f, 0.0f), (float)(Z - 1));
    const float4* in4 = (const float4*)inp + (size_t)b * X * Y * Z;
    const int xo0 = x0 * (Y * Z), xo1 = x1 * (Y * Z);
    const int yo0 = y0 * Z,       yo1 = y1 * Z;
    const float4 v000 = in4[xo0 + yo0 + z0];
    const float4 v001 = in4[xo0 + yo0 + z1];
    const float4 v010 = in4[xo0 + yo1 + z0];
    const float4 v011 = in4[xo0 + yo1 + z1];
    const float4 v100 = in4[xo1 + yo0 + z0];
    const float4 v101 = in4[xo1 + yo0 + z1];
    const float4 v110 = in4[xo1 + yo1 + z0];
    const float4 v111 = in4[xo1 + yo1 + z1];
    float4 r;
    #define LERP4(a, b_, wA, wB, dst)                  \
        dst.x = (a).x * (wA) + (b_).x * (wB);          \
        dst.y = (a).y * (wA) + (b_).y * (wB);          \
        dst.z = (a).z * (wA) + (b_).z * (wB);          \
        dst.w = (a).w * (wA) + (b_).w * (wB);
    float4 c00, c01, c10, c11, c0, c1;
    LERP4(v000, v001, wz1, wz0, c00);
    LERP4(v010, v011, wz1, wz0, c01);
    LERP4(v100, v101, wz1, wz0, c10);
    LERP4(v110, v111, wz1, wz0, c11);
    LERP4(c00, c01, wy1, wy0, c0);
    LERP4(c10, c11, wy1, wy0, c1);
    LERP4(c0, c1, wx1, wx0, r);
    #undef LERP4
    out[tid] = r;
}

extern "C" void kernel_launch(void* const* d_in, const int* in_sizes, int n_in,
                              void* d_out, int out_size, void* d_ws, size_t ws_size,
                              hipStream_t stream) {
    const float* inp    = (const float*)d_in[0];
    const float* coords = (const float*)d_in[1];
    float4* out = (float4*)d_out;

    if (ws_size < WS_NEEDED) {
        // Not enough scratch — direct (round-1) path.
        const int blocks = (NPTS + 255) / 256;
        resampler_direct_kernel<<<blocks, 256, 0, stream>>>(inp, coords, out);
        return;
    }

    char* ws = (char*)d_ws;
    float4* records = (float4*)ws;
    int* counts  = (int*)(ws + CNT_OFF);
    int* cursors = (int*)(ws + CUR_OFF);

    hipMemsetAsync(counts, 0, NBINS * sizeof(int), stream);
    hist_kernel<<<512, 256, 0, stream>>>(coords, counts);
    scan_kernel<<<1, NBINS, 0, stream>>>(counts, cursors);
    scatter_kernel<<<SC_NBLK, SC_THREADS, 0, stream>>>(coords, cursors, records);
    process_kernel<<<K4_NBLK, 256, 0, stream>>>(inp, records, out);
}

// Round 4
// 103.654 us; speedup vs baseline: 4.9136x; 1.1555x over previous
//
#include <hip/hip_runtime.h>

// Problem constants (fixed by the reference file)
constexpr int B  = 2;
constexpr int X  = 128, Y = 128, Z = 128, C = 4;
constexpr int OX = 96,  OY = 96,  OZ = 96;
constexpr int NPTS = B * OX * OY * OZ;          // 1,769,472 output voxels
constexpr int PTS_PER_BATCH = OX * OY * OZ;     // 884,736

// Spatial binning: 8^3-voxel cells -> 16 cells/dim -> 4096 cells/batch, 8192 bins.
// Cell region + replicate halo = 9^3 voxels * 16B = 11.7KB -> fits static LDS,
// so the 8 per-point gathers become LDS reads (no divergent-VMEM MSHR stalls).
constexpr int CELL_SHIFT = 3;                    // 8 voxels per cell
constexpr int CPD = X >> CELL_SHIFT;             // 16 cells per dim
constexpr int NBINS = B * CPD * CPD * CPD;       // 8192
constexpr int REG = (1 << CELL_SHIFT) + 1;       // 9 (region incl. halo)
constexpr int REG3 = REG * REG * REG;            // 729

// Workspace layout
constexpr size_t REC_BYTES  = (size_t)NPTS * 16;        // float4 records
constexpr size_t CNT_OFF    = REC_BYTES;                // int counts[NBINS]
constexpr size_t STARTS_OFF = CNT_OFF + (size_t)NBINS * 4;
constexpr size_t CUR_OFF    = STARTS_OFF + (size_t)NBINS * 4;
constexpr size_t WS_NEEDED  = CUR_OFF + (size_t)NBINS * 4;

__device__ __forceinline__ int point_bin(float cx, float cy, float cz, int b) {
    int x = min(max((int)floorf(cx), 0), X - 1) >> CELL_SHIFT;
    int y = min(max((int)floorf(cy), 0), Y - 1) >> CELL_SHIFT;
    int z = min(max((int)floorf(cz), 0), Z - 1) >> CELL_SHIFT;
    return (((b * CPD + x) * CPD + y) * CPD + z);
}

// K1: per-block LDS histogram of bin occupancy, merged with global atomics.
__global__ __launch_bounds__(256) void hist_kernel(
    const float* __restrict__ coords, int* __restrict__ counts)
{
    __shared__ int h[NBINS];
    for (int i = threadIdx.x; i < NBINS; i += 256) h[i] = 0;
    __syncthreads();
    for (int idx = blockIdx.x * 256 + threadIdx.x; idx < NPTS;
         idx += gridDim.x * 256) {
        const float cx = coords[(size_t)idx * 3 + 0];
        const float cy = coords[(size_t)idx * 3 + 1];
        const float cz = coords[(size_t)idx * 3 + 2];
        const int b = idx / PTS_PER_BATCH;
        atomicAdd(&h[point_bin(cx, cy, cz, b)], 1);
    }
    __syncthreads();
    for (int i = threadIdx.x; i < NBINS; i += 256)
        if (h[i]) atomicAdd(&counts[i], h[i]);
}

// K2: single-block exclusive scan of counts (8192) -> starts (pristine) and
// cursors (mutable copy for the scatter).
__global__ __launch_bounds__(1024) void scan_kernel(
    const int* __restrict__ counts, int* __restrict__ starts,
    int* __restrict__ cursors)
{
    __shared__ int partial[1024];
    const int t = threadIdx.x;
    int local[8];
    int sum = 0;
    #pragma unroll
    for (int j = 0; j < 8; ++j) { local[j] = counts[t * 8 + j]; sum += local[j]; }
    partial[t] = sum;
    __syncthreads();
    for (int off = 1; off < 1024; off <<= 1) {
        int add = (t >= off) ? partial[t - off] : 0;
        __syncthreads();
        partial[t] += add;
        __syncthreads();
    }
    int base = partial[t] - sum;   // exclusive prefix of this thread's chunk
    #pragma unroll
    for (int j = 0; j < 8; ++j) {
        starts[t * 8 + j]  = base;
        cursors[t * 8 + j] = base;
        base += local[j];
    }
}

// K3: LDS-aggregated two-phase scatter. 108 blocks x 1024 thr x 16 pts = NPTS.
// Phase A: LDS histogram. Phase B: one global atomic per occupied bin reserves
// a range; h[bin] becomes the bin's running global cursor. Phase C: place
// points via LDS atomics on h.
constexpr int SC_THREADS = 1024;
constexpr int SC_PPT     = 16;
constexpr int SC_PPB     = SC_THREADS * SC_PPT;          // 16384
constexpr int SC_NBLK    = NPTS / SC_PPB;                // 108 (exact)

__global__ __launch_bounds__(SC_THREADS) void scatter_kernel(
    const float* __restrict__ coords, int* __restrict__ cursors,
    float4* __restrict__ records)
{
    __shared__ int h[NBINS];      // counts -> global cursors
    const int t = threadIdx.x;
    const int blkBase = blockIdx.x * SC_PPB;

    for (int j = t; j < NBINS; j += SC_THREADS) h[j] = 0;
    __syncthreads();

    int bins[SC_PPT];
    #pragma unroll
    for (int p = 0; p < SC_PPT; ++p) {
        const int idx = blkBase + p * SC_THREADS + t;
        const float cx = coords[(size_t)idx * 3 + 0];
        const float cy = coords[(size_t)idx * 3 + 1];
        const float cz = coords[(size_t)idx * 3 + 2];
        const int b = idx / PTS_PER_BATCH;
        bins[p] = point_bin(cx, cy, cz, b);
        atomicAdd(&h[bins[p]], 1);
    }
    __syncthreads();

    for (int j = t; j < NBINS; j += SC_THREADS) {
        const int cnt = h[j];
        h[j] = cnt ? atomicAdd(&cursors[j], cnt) : 0;  // now: global cursor
    }
    __syncthreads();

    #pragma unroll
    for (int p = 0; p < SC_PPT; ++p) {
        const int idx = blkBase + p * SC_THREADS + t;
        const float cx = coords[(size_t)idx * 3 + 0];   // L2-hot re-read
        const float cy = coords[(size_t)idx * 3 + 1];
        const float cz = coords[(size_t)idx * 3 + 2];
        const int pos = atomicAdd(&h[bins[p]], 1);
        records[pos] = make_float4(cx, cy, cz, __int_as_float(idx));
    }
}

// K4: one block per bin. Stage the bin's 9^3 input region (replicate-clamped)
// into LDS with coalesced loads, then all 8 per-point gathers are LDS reads.
constexpr int NXCD = 8;
constexpr int K4_CPX = NBINS / NXCD;             // 1024 (exact)

__global__ __launch_bounds__(256) void cell_kernel(
    const float* __restrict__ inp, const float4* __restrict__ records,
    const int* __restrict__ starts, const int* __restrict__ counts,
    float4* __restrict__ out)
{
    // XCD-chunked swizzle: each XCD gets a contiguous 1024-bin range so
    // spatially adjacent bins (shared halo lines) live in one L2.
    const int pb = blockIdx.x;
    const int bin = (pb & (NXCD - 1)) * K4_CPX + (pb >> 3);

    const int b  = bin >> 12;
    const int cx = (bin >> 8) & 15;
    const int cy = (bin >> 4) & 15;
    const int cz = bin & 15;
    const int bx = cx << CELL_SHIFT, by = cy << CELL_SHIFT, bz = cz << CELL_SHIFT;

    __shared__ float4 tile[REG3];     // 11664 B

    const float4* in4 = (const float4*)inp + (size_t)b * X * Y * Z;
    for (int i = threadIdx.x; i < REG3; i += 256) {
        const int lx = i / (REG * REG);
        const int r  = i % (REG * REG);
        const int ly = r / REG;
        const int lz = r % REG;
        const int gx = min(bx + lx, X - 1);
        const int gy = min(by + ly, Y - 1);
        const int gz = min(bz + lz, Z - 1);
        tile[i] = in4[(gx * Y + gy) * Z + gz];
    }
    __syncthreads();

    const int start = starts[bin];
    const int cnt   = counts[bin];

    for (int k = threadIdx.x; k < cnt; k += 256) {
        const float4 rec = records[start + k];
        const float pcx = rec.x, pcy = rec.y, pcz = rec.z;
        const int ptid = __float_as_int(rec.w);

        const float fx = floorf(pcx), fy = floorf(pcy), fz = floorf(pcz);
        const float wx0 = pcx - fx, wy0 = pcy - fy, wz0 = pcz - fz;
        const float wx1 = 1.0f - wx0, wy1 = 1.0f - wy0, wz1 = 1.0f - wz0;

        // Clamped global indices (same semantics as reference), then local.
        const int x0 = (int)fminf(fmaxf(fx,        0.0f), (float)(X - 1)) - bx;
        const int x1 = (int)fminf(fmaxf(fx + 1.0f, 0.0f), (float)(X - 1)) - bx;
        const int y0 = (int)fminf(fmaxf(fy,        0.0f), (float)(Y - 1)) - by;
        const int y1 = (int)fminf(fmaxf(fy + 1.0f, 0.0f), (float)(Y - 1)) - by;
        const int z0 = (int)fminf(fmaxf(fz,        0.0f), (float)(Z - 1)) - bz;
        const int z1 = (int)fminf(fmaxf(fz + 1.0f, 0.0f), (float)(Z - 1)) - bz;

        const int xo0 = x0 * (REG * REG), xo1 = x1 * (REG * REG);
        const int yo0 = y0 * REG,         yo1 = y1 * REG;

        const float4 v000 = tile[xo0 + yo0 + z0];
        const float4 v001 = tile[xo0 + yo0 + z1];
        const float4 v010 = tile[xo0 + yo1 + z0];
        const float4 v011 = tile[xo0 + yo1 + z1];
        const float4 v100 = tile[xo1 + yo0 + z0];
        const float4 v101 = tile[xo1 + yo0 + z1];
        const float4 v110 = tile[xo1 + yo1 + z0];
        const float4 v111 = tile[xo1 + yo1 + z1];

        float4 r;
        #define LERP4(a, b_, wA, wB, dst)                  \
            dst.x = (a).x * (wA) + (b_).x * (wB);          \
            dst.y = (a).y * (wA) + (b_).y * (wB);          \
            dst.z = (a).z * (wA) + (b_).z * (wB);          \
            dst.w = (a).w * (wA) + (b_).w * (wB);
        float4 c00, c01, c10, c11, c0, c1;
        LERP4(v000, v001, wz1, wz0, c00);
        LERP4(v010, v011, wz1, wz0, c01);
        LERP4(v100, v101, wz1, wz0, c10);
        LERP4(v110, v111, wz1, wz0, c11);
        LERP4(c00, c01, wy1, wy0, c0);
        LERP4(c10, c11, wy1, wy0, c1);
        LERP4(c0, c1, wx1, wx0, r);
        #undef LERP4

        out[ptid] = r;   // scattered 16B store
    }
}

// Fallback (round-1 kernel) if workspace is too small for the sort pipeline.
__global__ __launch_bounds__(256) void resampler_direct_kernel(
    const float* __restrict__ inp, const float* __restrict__ coords,
    float4* __restrict__ out)
{
    const int tid = blockIdx.x * blockDim.x + threadIdx.x;
    if (tid >= NPTS) return;
    const int b = tid / PTS_PER_BATCH;
    const float cx = coords[(size_t)tid * 3 + 0];
    const float cy = coords[(size_t)tid * 3 + 1];
    const float cz = coords[(size_t)tid * 3 + 2];
    const float bx = floorf(cx), by = floorf(cy), bz = floorf(cz);
    const float wx0 = cx - bx, wy0 = cy - by, wz0 = cz - bz;
    const float wx1 = 1.0f - wx0, wy1 = 1.0f - wy0, wz1 = 1.0f - wz0;
    const int x0 = (int)fminf(fmaxf(bx,        0.0f), (float)(X - 1));
    const int x1 = (int)fminf(fmaxf(bx + 1.0f, 0.0f), (float)(X - 1));
    const int y0 = (int)fminf(fmaxf(by,        0.0f), (float)(Y - 1));
    const int y1 = (int)fminf(fmaxf(by + 1.0f, 0.0f), (float)(Y - 1));
    const int z0 = (int)fminf(fmaxf(bz,        0.0f), (float)(Z - 1));
    const int z1 = (int)fminf(fmaxf(bz + 1.0f, 0.0f), (float)(Z - 1));
    const float4* in4 = (const float4*)inp + (size_t)b * X * Y * Z;
    const int xo0 = x0 * (Y * Z), xo1 = x1 * (Y * Z);
    const int yo0 = y0 * Z,       yo1 = y1 * Z;
    const float4 v000 = in4[xo0 + yo0 + z0];
    const float4 v001 = in4[xo0 + yo0 + z1];
    const float4 v010 = in4[xo0 + yo1 + z0];
    const float4 v011 = in4[xo0 + yo1 + z1];
    const float4 v100 = in4[xo1 + yo0 + z0];
    const float4 v101 = in4[xo1 + yo0 + z1];
    const float4 v110 = in4[xo1 + yo1 + z0];
    const float4 v111 = in4[xo1 + yo1 + z1];
    float4 r;
    #define LERP4(a, b_, wA, wB, dst)                  \
        dst.x = (a).x * (wA) + (b_).x * (wB);          \
        dst.y = (a).y * (wA) + (b_).y * (wB);          \
        dst.z = (a).z * (wA) + (b_).z * (wB);          \
        dst.w = (a).w * (wA) + (b_).w * (wB);
    float4 c00, c01, c10, c11, c0, c1;
    LERP4(v000, v001, wz1, wz0, c00);
    LERP4(v010, v011, wz1, wz0, c01);
    LERP4(v100, v101, wz1, wz0, c10);
    LERP4(v110, v111, wz1, wz0, c11);
    LERP4(c00, c01, wy1, wy0, c0);
    LERP4(c10, c11, wy1, wy0, c1);
    LERP4(c0, c1, wx1, wx0, r);
    #undef LERP4
    out[tid] = r;
}

extern "C" void kernel_launch(void* const* d_in, const int* in_sizes, int n_in,
                              void* d_out, int out_size, void* d_ws, size_t ws_size,
                              hipStream_t stream) {
    const float* inp    = (const float*)d_in[0];
    const float* coords = (const float*)d_in[1];
    float4* out = (float4*)d_out;

    if (ws_size < WS_NEEDED) {
        const int blocks = (NPTS + 255) / 256;
        resampler_direct_kernel<<<blocks, 256, 0, stream>>>(inp, coords, out);
        return;
    }

    char* ws = (char*)d_ws;
    float4* records = (float4*)ws;
    int* counts  = (int*)(ws + CNT_OFF);
    int* starts  = (int*)(ws + STARTS_OFF);
    int* cursors = (int*)(ws + CUR_OFF);

    hipMemsetAsync(counts, 0, NBINS * sizeof(int), stream);
    hist_kernel<<<512, 256, 0, stream>>>(coords, counts);
    scan_kernel<<<1, 1024, 0, stream>>>(counts, starts, cursors);
    scatter_kernel<<<SC_NBLK, SC_THREADS, 0, stream>>>(coords, cursors, records);
    cell_kernel<<<NBINS, 256, 0, stream>>>(inp, records, starts, counts, out);
}

// Round 5
// 94.750 us; speedup vs baseline: 5.3754x; 1.0940x over previous
//
#include <hip/hip_runtime.h>

// Problem constants (fixed by the reference file)
constexpr int B  = 2;
constexpr int X  = 128, Y = 128, Z = 128, C = 4;
constexpr int OX = 96,  OY = 96,  OZ = 96;
constexpr int NPTS = B * OX * OY * OZ;          // 1,769,472 output voxels
constexpr int PTS_PER_BATCH = OX * OY * OZ;     // 884,736

// Spatial binning: cells of 8(x) x 16(y) x 16(z) voxels.
//   x-cells 16, y-cells 8, z-cells 8 -> 1024 cells/batch, 2048 bins.
// Region incl. replicate halo: 9 x 17 x 17 voxels * 16B = 41,616 B static LDS.
// ~864 points/bin. z-long cells give 272B-contiguous staging runs.
constexpr int NBINS = 2048;
constexpr int RX = 9, RY = 17, RZ = 17;
constexpr int REG3 = RX * RY * RZ;               // 2601

// Workspace layout
constexpr size_t REC_BYTES  = (size_t)NPTS * 16;        // float4 records
constexpr size_t CNT_OFF    = REC_BYTES;                // int counts[NBINS]
constexpr size_t STARTS_OFF = CNT_OFF + (size_t)NBINS * 4;
constexpr size_t CUR_OFF    = STARTS_OFF + (size_t)NBINS * 4;
constexpr size_t WS_NEEDED  = CUR_OFF + (size_t)NBINS * 4;

__device__ __forceinline__ int point_bin(float cx, float cy, float cz, int b) {
    const int x = min(max((int)floorf(cx), 0), X - 1) >> 3;   // 16 x-cells
    const int y = min(max((int)floorf(cy), 0), Y - 1) >> 4;   // 8 y-cells
    const int z = min(max((int)floorf(cz), 0), Z - 1) >> 4;   // 8 z-cells
    return b * 1024 + x * 64 + y * 8 + z;
}

// K1: per-block LDS histogram of bin occupancy, merged with global atomics.
__global__ __launch_bounds__(256) void hist_kernel(
    const float* __restrict__ coords, int* __restrict__ counts)
{
    __shared__ int h[NBINS];
    for (int i = threadIdx.x; i < NBINS; i += 256) h[i] = 0;
    __syncthreads();
    for (int idx = blockIdx.x * 256 + threadIdx.x; idx < NPTS;
         idx += gridDim.x * 256) {
        const float cx = coords[(size_t)idx * 3 + 0];
        const float cy = coords[(size_t)idx * 3 + 1];
        const float cz = coords[(size_t)idx * 3 + 2];
        const int b = idx / PTS_PER_BATCH;
        atomicAdd(&h[point_bin(cx, cy, cz, b)], 1);
    }
    __syncthreads();
    for (int i = threadIdx.x; i < NBINS; i += 256)
        if (h[i]) atomicAdd(&counts[i], h[i]);
}

// K2: single-block exclusive scan of counts (2048) -> starts + cursors.
__global__ __launch_bounds__(1024) void scan_kernel(
    const int* __restrict__ counts, int* __restrict__ starts,
    int* __restrict__ cursors)
{
    __shared__ int partial[1024];
    const int t = threadIdx.x;
    const int c0 = counts[t * 2], c1 = counts[t * 2 + 1];
    const int sum = c0 + c1;
    partial[t] = sum;
    __syncthreads();
    for (int off = 1; off < 1024; off <<= 1) {
        int add = (t >= off) ? partial[t - off] : 0;
        __syncthreads();
        partial[t] += add;
        __syncthreads();
    }
    const int base = partial[t] - sum;   // exclusive prefix
    starts[t * 2]      = base;
    cursors[t * 2]     = base;
    starts[t * 2 + 1]  = base + c0;
    cursors[t * 2 + 1] = base + c0;
}

// K3: LDS-aggregated two-phase scatter. 108 blocks x 1024 thr x 16 pts = NPTS.
// ~8 pts/bin/block -> 128B contiguous record runs (low write inflation).
constexpr int SC_THREADS = 1024;
constexpr int SC_PPT     = 16;
constexpr int SC_PPB     = SC_THREADS * SC_PPT;          // 16384
constexpr int SC_NBLK    = NPTS / SC_PPB;                // 108 (exact)

__global__ __launch_bounds__(SC_THREADS) void scatter_kernel(
    const float* __restrict__ coords, int* __restrict__ cursors,
    float4* __restrict__ records)
{
    __shared__ int h[NBINS];      // counts -> running global cursors
    const int t = threadIdx.x;
    const int blkBase = blockIdx.x * SC_PPB;

    h[t] = 0; h[t + 1024] = 0;
    __syncthreads();

    int bins[SC_PPT];
    #pragma unroll
    for (int p = 0; p < SC_PPT; ++p) {
        const int idx = blkBase + p * SC_THREADS + t;
        const float cx = coords[(size_t)idx * 3 + 0];
        const float cy = coords[(size_t)idx * 3 + 1];
        const float cz = coords[(size_t)idx * 3 + 2];
        const int b = idx / PTS_PER_BATCH;
        bins[p] = point_bin(cx, cy, cz, b);
        atomicAdd(&h[bins[p]], 1);
    }
    __syncthreads();

    #pragma unroll
    for (int j = 0; j < 2; ++j) {
        const int bi = t + j * 1024;
        const int cnt = h[bi];
        h[bi] = cnt ? atomicAdd(&cursors[bi], cnt) : 0;  // now: global cursor
    }
    __syncthreads();

    #pragma unroll
    for (int p = 0; p < SC_PPT; ++p) {
        const int idx = blkBase + p * SC_THREADS + t;
        const float cx = coords[(size_t)idx * 3 + 0];   // L2/L3-hot re-read
        const float cy = coords[(size_t)idx * 3 + 1];
        const float cz = coords[(size_t)idx * 3 + 2];
        const int pos = atomicAdd(&h[bins[p]], 1);
        records[pos] = make_float4(cx, cy, cz, __int_as_float(idx));
    }
}

// K4: one block per bin. Stage the bin's 9x17x17 input region (replicate-
// clamped) into LDS with coalesced loads (272B z-runs), then all 8 per-point
// gathers are LDS reads. 512 threads, ~864 pts/block, 3 blocks/CU resident.
constexpr int NXCD = 8;
constexpr int K4_CPX = NBINS / NXCD;             // 256 (exact)

__global__ __launch_bounds__(512) void cell_kernel(
    const float* __restrict__ inp, const float4* __restrict__ records,
    const int* __restrict__ starts, const int* __restrict__ counts,
    float4* __restrict__ out)
{
    // XCD-chunked swizzle: contiguous 256-bin range (x-slab) per XCD.
    const int pb = blockIdx.x;
    const int bin = (pb & (NXCD - 1)) * K4_CPX + (pb >> 3);

    const int b  = bin >> 10;
    const int cx = (bin >> 6) & 15;
    const int cy = (bin >> 3) & 7;
    const int cz = bin & 7;
    const int bx = cx << 3, by = cy << 4, bz = cz << 4;

    __shared__ float4 tile[REG3];     // 41,616 B

    const float4* in4 = (const float4*)inp + (size_t)b * X * Y * Z;
    for (int i = threadIdx.x; i < REG3; i += 512) {
        const int lx = i / (RY * RZ);
        const int r  = i % (RY * RZ);
        const int ly = r / RZ;
        const int lz = r % RZ;
        const int gx = min(bx + lx, X - 1);
        const int gy = min(by + ly, Y - 1);
        const int gz = min(bz + lz, Z - 1);
        tile[i] = in4[(gx * Y + gy) * Z + gz];
    }
    __syncthreads();

    const int start = starts[bin];
    const int cnt   = counts[bin];

    for (int k = threadIdx.x; k < cnt; k += 512) {
        const float4 rec = records[start + k];
        const float pcx = rec.x, pcy = rec.y, pcz = rec.z;
        const int ptid = __float_as_int(rec.w);

        const float fx = floorf(pcx), fy = floorf(pcy), fz = floorf(pcz);
        const float wx0 = pcx - fx, wy0 = pcy - fy, wz0 = pcz - fz;
        const float wx1 = 1.0f - wx0, wy1 = 1.0f - wy0, wz1 = 1.0f - wz0;

        // Clamped global indices (reference semantics), then cell-local.
        const int x0 = (int)fminf(fmaxf(fx,        0.0f), (float)(X - 1)) - bx;
        const int x1 = (int)fminf(fmaxf(fx + 1.0f, 0.0f), (float)(X - 1)) - bx;
        const int y0 = (int)fminf(fmaxf(fy,        0.0f), (float)(Y - 1)) - by;
        const int y1 = (int)fminf(fmaxf(fy + 1.0f, 0.0f), (float)(Y - 1)) - by;
        const int z0 = (int)fminf(fmaxf(fz,        0.0f), (float)(Z - 1)) - bz;
        const int z1 = (int)fminf(fmaxf(fz + 1.0f, 0.0f), (float)(Z - 1)) - bz;

        const int xo0 = x0 * (RY * RZ), xo1 = x1 * (RY * RZ);
        const int yo0 = y0 * RZ,        yo1 = y1 * RZ;

        const float4 v000 = tile[xo0 + yo0 + z0];
        const float4 v001 = tile[xo0 + yo0 + z1];
        const float4 v010 = tile[xo0 + yo1 + z0];
        const float4 v011 = tile[xo0 + yo1 + z1];
        const float4 v100 = tile[xo1 + yo0 + z0];
        const float4 v101 = tile[xo1 + yo0 + z1];
        const float4 v110 = tile[xo1 + yo1 + z0];
        const float4 v111 = tile[xo1 + yo1 + z1];

        float4 r;
        #define LERP4(a, b_, wA, wB, dst)                  \
            dst.x = (a).x * (wA) + (b_).x * (wB);          \
            dst.y = (a).y * (wA) + (b_).y * (wB);          \
            dst.z = (a).z * (wA) + (b_).z * (wB);          \
            dst.w = (a).w * (wA) + (b_).w * (wB);
        float4 c00, c01, c10, c11, c0, c1;
        LERP4(v000, v001, wz1, wz0, c00);
        LERP4(v010, v011, wz1, wz0, c01);
        LERP4(v100, v101, wz1, wz0, c10);
        LERP4(v110, v111, wz1, wz0, c11);
        LERP4(c00, c01, wy1, wy0, c0);
        LERP4(c10, c11, wy1, wy0, c1);
        LERP4(c0, c1, wx1, wx0, r);
        #undef LERP4

        out[ptid] = r;   // scattered 16B store
    }
}

// Fallback (round-1 kernel) if workspace is too small for the sort pipeline.
__global__ __launch_bounds__(256) void resampler_direct_kernel(
    const float* __restrict__ inp, const float* __restrict__ coords,
    float4* __restrict__ out)
{
    const int tid = blockIdx.x * blockDim.x + threadIdx.x;
    if (tid >= NPTS) return;
    const int b = tid / PTS_PER_BATCH;
    const float cx = coords[(size_t)tid * 3 + 0];
    const float cy = coords[(size_t)tid * 3 + 1];
    const float cz = coords[(size_t)tid * 3 + 2];
    const float bx = floorf(cx), by = floorf(cy), bz = floorf(cz);
    const float wx0 = cx - bx, wy0 = cy - by, wz0 = cz - bz;
    const float wx1 = 1.0f - wx0, wy1 = 1.0f - wy0, wz1 = 1.0f - wz0;
    const int x0 = (int)fminf(fmaxf(bx,        0.0f), (float)(X - 1));
    const int x1 = (int)fminf(fmaxf(bx + 1.0f, 0.0f), (float)(X - 1));
    const int y0 = (int)fminf(fmaxf(by,        0.0f), (float)(Y - 1));
    const int y1 = (int)fminf(fmaxf(by + 1.0f, 0.0f), (float)(Y - 1));
    const int z0 = (int)fminf(fmaxf(bz,        0.0f), (float)(Z - 1));
    const int z1 = (int)fminf(fmaxf(bz + 1.0f, 0.0f), (float)(Z - 1));
    const float4* in4 = (const float4*)inp + (size_t)b * X * Y * Z;
    const int xo0 = x0 * (Y * Z), xo1 = x1 * (Y * Z);
    const int yo0 = y0 * Z,       yo1 = y1 * Z;
    const float4 v000 = in4[xo0 + yo0 + z0];
    const float4 v001 = in4[xo0 + yo0 + z1];
    const float4 v010 = in4[xo0 + yo1 + z0];
    const float4 v011 = in4[xo0 + yo1 + z1];
    const float4 v100 = in4[xo1 + yo0 + z0];
    const float4 v101 = in4[xo1 + yo0 + z1];
    const float4 v110 = in4[xo1 + yo1 + z0];
    const float4 v111 = in4[xo1 + yo1 + z1];
    float4 r;
    #define LERP4(a, b_, wA, wB, dst)                  \
        dst.x = (a).x * (wA) + (b_).x * (wB);          \
        dst.y = (a).y * (wA) + (b_).y * (wB);          \
        dst.z = (a).z * (wA) + (b_).z * (wB);          \
        dst.w = (a).w * (wA) + (b_).w * (wB);
    float4 c00, c01, c10, c11, c0, c1;
    LERP4(v000, v001, wz1, wz0, c00);
    LERP4(v010, v011, wz1, wz0, c01);
    LERP4(v100, v101, wz1, wz0, c10);
    LERP4(v110, v111, wz1, wz0, c11);
    LERP4(c00, c01, wy1, wy0, c0);
    LERP4(c10, c11, wy1, wy0, c1);
    LERP4(c0, c1, wx1, wx0, r);
    #undef LERP4
    out[tid] = r;
}

extern "C" void kernel_launch(void* const* d_in, const int* in_sizes, int n_in,
                              void* d_out, int out_size, void* d_ws, size_t ws_size,
                              hipStream_t stream) {
    const float* inp    = (const float*)d_in[0];
    const float* coords = (const float*)d_in[1];
    float4* out = (float4*)d_out;

    if (ws_size < WS_NEEDED) {
        const int blocks = (NPTS + 255) / 256;
        resampler_direct_kernel<<<blocks, 256, 0, stream>>>(inp, coords, out);
        return;
    }

    char* ws = (char*)d_ws;
    float4* records = (float4*)ws;
    int* counts  = (int*)(ws + CNT_OFF);
    int* starts  = (int*)(ws + STARTS_OFF);
    int* cursors = (int*)(ws + CUR_OFF);

    hipMemsetAsync(counts, 0, NBINS * sizeof(int), stream);
    hist_kernel<<<512, 256, 0, stream>>>(coords, counts);
    scan_kernel<<<1, 1024, 0, stream>>>(counts, starts, cursors);
    scatter_kernel<<<SC_NBLK, SC_THREADS, 0, stream>>>(coords, cursors, records);
    cell_kernel<<<NBINS, 512, 0, stream>>>(inp, records, starts, counts, out);
}